// Round 16
// baseline (241.312 us; speedup 1.0000x reference)
//
#include <hip/hip_runtime.h>
#include <hip/hip_bf16.h>
#include <math.h>

#define NPART 8

typedef __attribute__((ext_vector_type(8))) short bf16x8;
typedef __attribute__((ext_vector_type(4))) float f32x4;

__device__ __forceinline__ float lrelu(float v) { return fmaxf(v, 0.2f * v); }

__device__ __forceinline__ unsigned fenc(float f) {
    unsigned u = __float_as_uint(f);
    return (u & 0x80000000u) ? ~u : (u | 0x80000000u);
}
__device__ __forceinline__ float fdec(unsigned u) {
    return __uint_as_float((u & 0x80000000u) ? (u & 0x7FFFFFFFu) : ~u);
}
__device__ __forceinline__ unsigned short f2bf(float f) {
    union { __hip_bfloat16 b; unsigned short u; } cv;
    cv.b = __float2bfloat16(f);
    return cv.u;
}
__device__ __forceinline__ float bflo(unsigned u) { return __uint_as_float(u << 16); }
__device__ __forceinline__ float bfhi(unsigned u) { return __uint_as_float(u & 0xFFFF0000u); }

// ---- setup: x->xb bf16, W->Wt bf16, cursor/self-loop/gmax/dummy-row inits ----

__global__ void setup_all(const float* __restrict__ x,
                          const float* __restrict__ W1, const float* __restrict__ W2,
                          const float* __restrict__ W3,
                          unsigned short* __restrict__ xb,
                          unsigned short* __restrict__ Wt1, unsigned short* __restrict__ Wt2,
                          unsigned short* __restrict__ Wt3,
                          int* __restrict__ cursor, unsigned short* __restrict__ srcs,
                          unsigned* __restrict__ gmax, unsigned short* __restrict__ hb,
                          int N, int GX) {
    int b = blockIdx.x, t = threadIdx.x;
    if (b < GX) {                                   // role A: x conversion + inits
        int i = b * 256 + t;
        if (i < N * 32) {
            float4 v = ((const float4*)x)[i];
            ushort4 o;
            o.x = f2bf(v.x); o.y = f2bf(v.y); o.z = f2bf(v.z); o.w = f2bf(v.w);
            ((ushort4*)xb)[i] = o;
        }
        if (i < N) {
            cursor[i] = (i << 6) + 1;               // slot 0 = self-loop
            srcs[(size_t)i << 6] = (unsigned short)i;
        }
        if (i < 12) gmax[i] = fenc(-1e30f);
        if (i < 64) ((unsigned*)hb)[(size_t)N * 64 + i] = 0;   // dummy row N = 0
        return;
    }
    {                                               // role B: W transpose-convert
        int j = (b - GX) * 256 + t;
        if (j < 3 * 16384) {
            int mm = j >> 14, e = j & 16383;
            const float* W = (mm == 0) ? W1 : (mm == 1) ? W2 : W3;
            unsigned short* Wt = (mm == 0) ? Wt1 : (mm == 1) ? Wt2 : Wt3;
            int k = e >> 7, c = e & 127;
            Wt[c * 128 + k] = f2bf(W[e]);           // Wt[col][k]
        }
    }
}

// ---- scatter into fixed-capacity CSR (64 slots/node), XCD-partitioned, standalone ----

__global__ void scatter_part(const int* __restrict__ ei, int E, int N,
                             int* cursor, unsigned short* __restrict__ srcs, int pn) {
    int part = blockIdx.x & (NPART - 1);
    int nb = gridDim.x >> 3;
    int chunk = blockIdx.x >> 3;
    int stride = nb * blockDim.x;
    int lo = part * pn, hi = min(lo + pn, N);
    for (int i = chunk * blockDim.x + threadIdx.x; i < E; i += stride) {
        int d = ei[E + i];
        if (d >= lo && d < hi) {
            int pos = atomicAdd(&cursor[d], 1);
            if (pos - (d << 6) < 64) srcs[pos] = (unsigned short)ei[i];
        }
    }
}

// ---- pad body (runs as tail of gemm2 dispatch) ----

__device__ __forceinline__ void pad_body(int pb, int t, int* __restrict__ cursor,
                                         unsigned short* __restrict__ srcs, int N) {
    int n = pb * 256 + t;
    if (n >= N) return;
    int dr = cursor[n] - (n << 6);
    if (dr > 64) dr = 64;
    int q = (dr + 3) >> 2;
    for (int k = dr; k < q * 4; k++) srcs[(n << 6) + k] = (unsigned short)N;
    cursor[n] = q;                                  // cursor -> quad count (layers 2,3)
}

// ---- MFMA GEMM body + fused fp32-epilogue logits + per-head global max ----
// per wave: 16 rows x 128 cols, K=128 (R11-proven form)

template <int H>
__device__ __forceinline__ void gemm_body(int bid, const unsigned short* __restrict__ xb,
                                          const unsigned short* __restrict__ Wt,
                                          const float* __restrict__ a_s,
                                          const float* __restrict__ a_d,
                                          unsigned short* __restrict__ hb,
                                          float* __restrict__ asb,
                                          float* __restrict__ adb,
                                          unsigned* __restrict__ gmax, int N) {
    constexpr int HH = (H == 4) ? 4 : 1;
    __shared__ float smax[4][HH];
    int t = threadIdx.x;
    int wave = t >> 6, lane = t & 63;
    int lrow = lane & 15;
    int kg = lane >> 4;
    int row0 = bid * 64 + wave * 16;
    int arow = min(row0 + lrow, N - 1);
    const bf16x8* ap = (const bf16x8*)(xb + (size_t)arow * 128 + kg * 8);

    f32x4 acc[8];
#pragma unroll
    for (int ct = 0; ct < 8; ct++) acc[ct] = (f32x4)0.f;
#pragma unroll
    for (int kk = 0; kk < 4; kk++) {
        bf16x8 a = ap[kk * 4];
#pragma unroll
        for (int ct = 0; ct < 8; ct++) {
            const bf16x8* bp = (const bf16x8*)(Wt + (size_t)(ct * 16 + lrow) * 128 + kk * 32 + kg * 8);
            acc[ct] = __builtin_amdgcn_mfma_f32_16x16x32_bf16(a, *bp, acc[ct], 0, 0, 0);
        }
    }
    int orow = row0 + kg * 4;
#pragma unroll
    for (int reg = 0; reg < 4; reg++) {
        int r = orow + reg;
        if (r < N) {
#pragma unroll
            for (int ct = 0; ct < 8; ct++)
                hb[(size_t)r * 128 + ct * 16 + lrow] = f2bf(acc[ct][reg]);
        }
    }
    float ps[4][HH], pd[4][HH];
#pragma unroll
    for (int reg = 0; reg < 4; reg++)
#pragma unroll
        for (int hd = 0; hd < HH; hd++) { ps[reg][hd] = 0.f; pd[reg][hd] = 0.f; }
#pragma unroll
    for (int ct = 0; ct < 8; ct++) {
        int hd = (H == 4) ? (ct >> 1) : 0;
        float asv = a_s[ct * 16 + lrow];
        float adv = a_d[ct * 16 + lrow];
#pragma unroll
        for (int reg = 0; reg < 4; reg++) {
            ps[reg][hd] += acc[ct][reg] * asv;
            pd[reg][hd] += acc[ct][reg] * adv;
        }
    }
    for (int o = 1; o < 16; o <<= 1) {
#pragma unroll
        for (int reg = 0; reg < 4; reg++)
#pragma unroll
            for (int hd = 0; hd < HH; hd++) {
                ps[reg][hd] += __shfl_xor(ps[reg][hd], o);
                pd[reg][hd] += __shfl_xor(pd[reg][hd], o);
            }
    }
    if (lrow < HH) {
        int hd = lrow;
#pragma unroll
        for (int reg = 0; reg < 4; reg++) {
            int r = orow + reg;
            if (r < N) {
                asb[(size_t)r * H + hd] = ps[reg][hd];
                adb[(size_t)r * H + hd] = pd[reg][hd];
            }
        }
    }
    float wm[HH];
#pragma unroll
    for (int hd = 0; hd < HH; hd++) {
        float m = fmaxf(fmaxf(ps[0][hd], ps[1][hd]), fmaxf(ps[2][hd], ps[3][hd]));
        m = fmaxf(m, __shfl_xor(m, 16));
        m = fmaxf(m, __shfl_xor(m, 32));
        wm[hd] = m;
    }
    if (lane == 0)
#pragma unroll
        for (int hd = 0; hd < HH; hd++) smax[wave][hd] = wm[hd];
    __syncthreads();
    if (t < HH) {
        float m = fmaxf(fmaxf(smax[0][t], smax[1][t]), fmaxf(smax[2][t], smax[3][t]));
        atomicMax(&gmax[t], fenc(m));
    }
    if (bid == 0 && t == 0) {
#pragma unroll
        for (int hd = 0; hd < HH; hd++) asb[(size_t)N * H + hd] = -1e30f;  // dummy -> p=0
    }
}

// ---- dispatches ----

__global__ __launch_bounds__(256) void gemm1_k(const unsigned short* __restrict__ xb,
                                               const unsigned short* __restrict__ Wt,
                                               const float* __restrict__ a_s,
                                               const float* __restrict__ a_d,
                                               unsigned short* __restrict__ hb,
                                               float* __restrict__ asb,
                                               float* __restrict__ adb,
                                               unsigned* __restrict__ gmax, int N) {
    gemm_body<4>(blockIdx.x, xb, Wt, a_s, a_d, hb, asb, adb, gmax, N);
}

__global__ __launch_bounds__(256) void gemm2_pad(const unsigned short* __restrict__ xb,
                                                 const unsigned short* __restrict__ Wt,
                                                 const float* __restrict__ a_s,
                                                 const float* __restrict__ a_d,
                                                 unsigned short* __restrict__ hb,
                                                 float* __restrict__ asb,
                                                 float* __restrict__ adb,
                                                 unsigned* __restrict__ gmax,
                                                 int* __restrict__ cursor,
                                                 unsigned short* __restrict__ srcs,
                                                 int N, int gb) {
    if ((int)blockIdx.x < gb)
        gemm_body<4>(blockIdx.x, xb, Wt, a_s, a_d, hb, asb, adb, gmax, N);
    else
        pad_body(blockIdx.x - gb, threadIdx.x, cursor, srcs, N);
}

__global__ __launch_bounds__(256) void gemm3_k(const unsigned short* __restrict__ xb,
                                               const unsigned short* __restrict__ Wt,
                                               const float* __restrict__ a_s,
                                               const float* __restrict__ a_d,
                                               unsigned short* __restrict__ hb,
                                               float* __restrict__ asb,
                                               float* __restrict__ adb,
                                               unsigned* __restrict__ gmax, int N) {
    gemm_body<1>(blockIdx.x, xb, Wt, a_s, a_d, hb, asb, adb, gmax, N);
}

// ---- aggregation: quarter-wave per dst, exp-dedup, 2-quad pipeline.
//      MASK=true: tail-quad masking from raw cursor (layer 1, pre-pad) ----

template <int H, bool RELU, bool OUTBF, bool MASK>
__global__ __launch_bounds__(256) void aggregate10(const unsigned short* __restrict__ hb,
                                                   const unsigned short* __restrict__ srcs,
                                                   const int* __restrict__ qn,
                                                   const float* __restrict__ asb,
                                                   const float* __restrict__ adb,
                                                   const unsigned* __restrict__ gmax,
                                                   const float* __restrict__ bias,
                                                   void* __restrict__ outv, int N) {
    int n = (blockIdx.x * 256 + threadIdx.x) >> 4;     // quarter-wave id = node
    if (n >= N) return;
    unsigned l = threadIdx.x & 15;
    unsigned ht = (H == 4) ? (l >> 2) : 0;
    int base = (threadIdx.x & 63) & ~15;               // quarter-wave base lane in wave
    float adn = adb[(unsigned)n * H + ht];
    float m = lrelu(fdec(gmax[ht]) + adn);
    const unsigned short* sp = srcs + ((size_t)n << 6);
    const uint4* hrow = (const uint4*)hb;              // 16 uint4 per 128-ch row
    int cv = qn[n];
    int nb, rem;
    if (MASK) {
        int dr = cv - (n << 6);
        dr = min(dr, 64);
        nb = (dr + 3) >> 2;
        rem = dr - ((nb - 1) << 2);                    // valid slots in final quad, 1..4
    } else {
        nb = cv;
        rem = 4;
    }
    float a0 = 0.f, a1 = 0.f, a2 = 0.f, a3 = 0.f;
    float a4 = 0.f, a5 = 0.f, a6 = 0.f, a7 = 0.f, den = 0.f;

    ushort4 sq = *(const ushort4*)sp;
    uint4 u0 = hrow[(unsigned)sq.x * 16u + l];
    uint4 u1 = hrow[(unsigned)sq.y * 16u + l];
    uint4 u2 = hrow[(unsigned)sq.z * 16u + l];
    uint4 u3 = hrow[(unsigned)sq.w * 16u + l];
    for (int j = 0; j < nb; j++) {
        int jn = (j + 1 < nb) ? j + 1 : j;
        ushort4 sn = *(const ushort4*)(sp + jn * 4);
        uint4 v0 = hrow[(unsigned)sn.x * 16u + l];     // next-quad rows in flight
        uint4 v1 = hrow[(unsigned)sn.y * 16u + l];
        uint4 v2 = hrow[(unsigned)sn.z * 16u + l];
        uint4 v3 = hrow[(unsigned)sn.w * 16u + l];
        unsigned sown = sp[j * 4 + (l & 3)];
        float e = asb[sown * H + ht];
        float pown = __expf(lrelu(e + adn) - m);
        float p0 = __shfl(pown, base + (int)ht * 4 + 0);
        float p1 = __shfl(pown, base + (int)ht * 4 + 1);
        float p2 = __shfl(pown, base + (int)ht * 4 + 2);
        float p3 = __shfl(pown, base + (int)ht * 4 + 3);
        if (MASK) {
            int limit = (j == nb - 1) ? rem : 4;
            p1 = (1 < limit) ? p1 : 0.f;
            p2 = (2 < limit) ? p2 : 0.f;
            p3 = (3 < limit) ? p3 : 0.f;
        }
        a0 += p0 * bflo(u0.x); a1 += p0 * bfhi(u0.x); a2 += p0 * bflo(u0.y); a3 += p0 * bfhi(u0.y);
        a4 += p0 * bflo(u0.z); a5 += p0 * bfhi(u0.z); a6 += p0 * bflo(u0.w); a7 += p0 * bfhi(u0.w);
        a0 += p1 * bflo(u1.x); a1 += p1 * bfhi(u1.x); a2 += p1 * bflo(u1.y); a3 += p1 * bfhi(u1.y);
        a4 += p1 * bflo(u1.z); a5 += p1 * bfhi(u1.z); a6 += p1 * bflo(u1.w); a7 += p1 * bfhi(u1.w);
        a0 += p2 * bflo(u2.x); a1 += p2 * bfhi(u2.x); a2 += p2 * bflo(u2.y); a3 += p2 * bfhi(u2.y);
        a4 += p2 * bflo(u2.z); a5 += p2 * bfhi(u2.z); a6 += p2 * bflo(u2.w); a7 += p2 * bfhi(u2.w);
        a0 += p3 * bflo(u3.x); a1 += p3 * bfhi(u3.x); a2 += p3 * bflo(u3.y); a3 += p3 * bfhi(u3.y);
        a4 += p3 * bflo(u3.z); a5 += p3 * bfhi(u3.z); a6 += p3 * bflo(u3.w); a7 += p3 * bfhi(u3.w);
        den += p0 + p1 + p2 + p3;
        sq = sn; u0 = v0; u1 = v1; u2 = v2; u3 = v3;
    }
    float inv = 1.f / (den + 1e-16f);
    unsigned c = l * 8;
    float4 bv0 = *(const float4*)&bias[c];
    float4 bv1 = *(const float4*)&bias[c + 4];
    float o0 = a0 * inv + bv0.x, o1 = a1 * inv + bv0.y;
    float o2 = a2 * inv + bv0.z, o3 = a3 * inv + bv0.w;
    float o4 = a4 * inv + bv1.x, o5 = a5 * inv + bv1.y;
    float o6 = a6 * inv + bv1.z, o7 = a7 * inv + bv1.w;
    if (RELU) {
        o0 = fmaxf(o0, 0.f); o1 = fmaxf(o1, 0.f); o2 = fmaxf(o2, 0.f); o3 = fmaxf(o3, 0.f);
        o4 = fmaxf(o4, 0.f); o5 = fmaxf(o5, 0.f); o6 = fmaxf(o6, 0.f); o7 = fmaxf(o7, 0.f);
    }
    if (OUTBF) {
        uint4 st;
        st.x = (unsigned)f2bf(o0) | ((unsigned)f2bf(o1) << 16);
        st.y = (unsigned)f2bf(o2) | ((unsigned)f2bf(o3) << 16);
        st.z = (unsigned)f2bf(o4) | ((unsigned)f2bf(o5) << 16);
        st.w = (unsigned)f2bf(o6) | ((unsigned)f2bf(o7) << 16);
        *(uint4*)&((unsigned short*)outv)[(size_t)n * 128 + c] = st;
    } else {
        float* op = (float*)outv + (size_t)n * 128 + c;
        float4 s0; s0.x = o0; s0.y = o1; s0.z = o2; s0.w = o3;
        float4 s1; s1.x = o4; s1.y = o5; s1.z = o6; s1.w = o7;
        *(float4*)op = s0;
        *(float4*)(op + 4) = s1;
    }
}

// ---------------- launch ----------------

extern "C" void kernel_launch(void* const* d_in, const int* in_sizes, int n_in,
                              void* d_out, int out_size, void* d_ws, size_t ws_size,
                              hipStream_t stream) {
    const float* x   = (const float*)d_in[0];
    const int*   ei  = (const int*)d_in[1];
    const float* W1  = (const float*)d_in[2];
    const float* as1 = (const float*)d_in[3];
    const float* ad1 = (const float*)d_in[4];
    const float* b1  = (const float*)d_in[5];
    const float* W2  = (const float*)d_in[6];
    const float* as2 = (const float*)d_in[7];
    const float* ad2 = (const float*)d_in[8];
    const float* b2  = (const float*)d_in[9];
    const float* W3  = (const float*)d_in[10];
    const float* as3 = (const float*)d_in[11];
    const float* ad3 = (const float*)d_in[12];
    const float* b3  = (const float*)d_in[13];

    const int N = in_sizes[0] / 128;
    const int E = in_sizes[1] / 2;
    const int PN = (N + NPART - 1) / NPART;

    char* w = (char*)d_ws;
    size_t woff = 0;
    auto alloc = [&](size_t bytes) -> void* {
        void* p = w + woff;
        woff = (woff + bytes + 255) & ~(size_t)255;
        return p;
    };
    int*      cursor = (int*)alloc((size_t)(N + 1) * 4);
    unsigned short* srcs = (unsigned short*)alloc(((size_t)N * 64 + 64) * 2);
    float*    asb    = (float*)alloc((size_t)(N + 1) * 4 * 4);
    float*    adb    = (float*)alloc((size_t)(N + 1) * 4 * 4);
    unsigned* gmax   = (unsigned*)alloc(16 * 4);
    unsigned short* hb  = (unsigned short*)alloc((size_t)(N + 1) * 128 * 2);
    unsigned short* xb  = (unsigned short*)alloc((size_t)N * 128 * 2);
    unsigned short* Wt1 = (unsigned short*)alloc(128 * 128 * 2);
    unsigned short* Wt2 = (unsigned short*)alloc(128 * 128 * 2);
    unsigned short* Wt3 = (unsigned short*)alloc(128 * 128 * 2);
    float* outf = (float*)d_out;

    const int GX = (N * 32 + 255) / 256;
    const int gb = (N + 63) / 64;
    const int ga = (N * 16 + 255) / 256;
    const int PB = (N + 255) / 256;

    // 1) setup: conversions + cursor/self-loop/gmax/dummy-row inits
    setup_all<<<GX + 192, 256, 0, stream>>>(x, W1, W2, W3, xb, Wt1, Wt2, Wt3,
                                            cursor, srcs, gmax, hb, N, GX);

    // 2) CSR scatter (standalone, full parallelism)
    scatter_part<<<2048, 256, 0, stream>>>(ei, E, N, cursor, srcs, PN);

    // 3) layer-1 GEMM
    gemm1_k<<<gb, 256, 0, stream>>>(xb, Wt1, as1, ad1, hb, asb, adb, gmax + 0, N);

    // 4) layer-1 aggregate with inline tail-masking (raw cursor)
    aggregate10<4, true, true, true><<<ga, 256, 0, stream>>>(hb, srcs, cursor, asb, adb,
                                                             gmax + 0, b1, xb, N);

    // 5) layer-2 GEMM || pad_fill (pads srcs, cursor -> quad count)
    gemm2_pad<<<gb + PB, 256, 0, stream>>>(xb, Wt2, as2, ad2, hb, asb, adb, gmax + 4,
                                           cursor, srcs, N, gb);

    // 6) layer-2 aggregate (padded fast path)
    aggregate10<4, true, true, false><<<ga, 256, 0, stream>>>(hb, srcs, cursor, asb, adb,
                                                              gmax + 4, b2, xb, N);

    // 7) layer-3 GEMM (H=1)
    gemm3_k<<<gb, 256, 0, stream>>>(xb, Wt3, as3, ad3, hb, asb, adb, gmax + 8, N);

    // 8) layer-3 aggregate (fp32 out)
    aggregate10<1, false, false, false><<<ga, 256, 0, stream>>>(hb, srcs, cursor, asb, adb,
                                                                gmax + 8, b3, outf, N);
}

// Round 17
// 230.955 us; speedup vs baseline: 1.0448x; 1.0448x over previous
//
#include <hip/hip_runtime.h>
#include <hip/hip_bf16.h>
#include <math.h>

#define SB 1024          // scatter blocks inside fused gemm1 dispatch
#define GB 512           // B-resident gemm blocks (4 waves each)

typedef __attribute__((ext_vector_type(8))) short bf16x8;
typedef __attribute__((ext_vector_type(4))) float f32x4;

__device__ __forceinline__ float lrelu(float v) { return fmaxf(v, 0.2f * v); }

__device__ __forceinline__ unsigned fenc(float f) {
    unsigned u = __float_as_uint(f);
    return (u & 0x80000000u) ? ~u : (u | 0x80000000u);
}
__device__ __forceinline__ float fdec(unsigned u) {
    return __uint_as_float((u & 0x80000000u) ? (u & 0x7FFFFFFFu) : ~u);
}
__device__ __forceinline__ unsigned short f2bf(float f) {
    union { __hip_bfloat16 b; unsigned short u; } cv;
    cv.b = __float2bfloat16(f);
    return cv.u;
}
__device__ __forceinline__ float bflo(unsigned u) { return __uint_as_float(u << 16); }
__device__ __forceinline__ float bfhi(unsigned u) { return __uint_as_float(u & 0xFFFF0000u); }

// ---- setup: x->xb bf16, W->Wt bf16, cursor/self-loop/gmax/dummy-row inits ----

__global__ void setup_all(const float* __restrict__ x,
                          const float* __restrict__ W1, const float* __restrict__ W2,
                          const float* __restrict__ W3,
                          unsigned short* __restrict__ xb,
                          unsigned short* __restrict__ Wt1, unsigned short* __restrict__ Wt2,
                          unsigned short* __restrict__ Wt3,
                          int* __restrict__ cursor, unsigned short* __restrict__ srcs,
                          unsigned* __restrict__ gmax, unsigned short* __restrict__ hb,
                          int N, int GX) {
    int b = blockIdx.x, t = threadIdx.x;
    if (b < GX) {                                   // role A: x conversion + inits
        int i = b * 256 + t;
        if (i < N * 32) {
            float4 v = ((const float4*)x)[i];
            ushort4 o;
            o.x = f2bf(v.x); o.y = f2bf(v.y); o.z = f2bf(v.z); o.w = f2bf(v.w);
            ((ushort4*)xb)[i] = o;
        }
        if (i < N) {
            cursor[i] = (i << 6) + 1;               // slot 0 = self-loop
            srcs[(size_t)i << 6] = (unsigned short)i;
        }
        if (i < 12) gmax[i] = fenc(-1e30f);
        if (i < 64) ((unsigned*)hb)[(size_t)N * 64 + i] = 0;   // dummy row N = 0
        return;
    }
    {                                               // role B: W transpose-convert
        int j = (b - GX) * 256 + t;
        if (j < 3 * 16384) {
            int mm = j >> 14, e = j & 16383;
            const float* W = (mm == 0) ? W1 : (mm == 1) ? W2 : W3;
            unsigned short* Wt = (mm == 0) ? Wt1 : (mm == 1) ? Wt2 : Wt3;
            int k = e >> 7, c = e & 127;
            Wt[c * 128 + k] = f2bf(W[e]);           // Wt[col][k]
        }
    }
}

// ---- scatter body (XCD-partitioned, fixed-capacity CSR 64 slots/node) ----

__device__ __forceinline__ void scatter_body(int sb, int t, const int* __restrict__ ei,
                                             int E, int N, int* cursor,
                                             unsigned short* __restrict__ srcs, int pn) {
    int part = sb & 7;
    int chunk = sb >> 3;
    int stride = (SB >> 3) * 256;
    int lo = part * pn, hi = min(lo + pn, N);
    for (int i = chunk * 256 + t; i < E; i += stride) {
        int d = ei[E + i];
        if (d >= lo && d < hi) {
            int pos = atomicAdd(&cursor[d], 1);
            if (pos - (d << 6) < 64) srcs[pos] = (unsigned short)ei[i];
        }
    }
}

// ---- pad body (runs as tail of gemm2 dispatch) ----

__device__ __forceinline__ void pad_body(int pb, int t, int* __restrict__ cursor,
                                         unsigned short* __restrict__ srcs, int N) {
    int n = pb * 256 + t;
    if (n >= N) return;
    int dr = cursor[n] - (n << 6);
    if (dr > 64) dr = 64;
    int q = (dr + 3) >> 2;
    for (int k = dr; k < q * 4; k++) srcs[(n << 6) + k] = (unsigned short)N;
    cursor[n] = q;                                  // cursor -> quad count (layers 2,3)
}

// ---- B-resident MFMA GEMM body: wave holds full Wt in VGPRs, loops over 16-row tiles.
//      Epilogue: fp32 LDS transpose -> row-contiguous logits (no big shuffle tree) +
//      wide bf16 stores. ----

template <int H>
__device__ __forceinline__ void gemm_body2(int wid, int nwaves, int wave,
                                           const unsigned short* __restrict__ xb,
                                           const unsigned short* __restrict__ Wt,
                                           const float* __restrict__ a_s,
                                           const float* __restrict__ a_d,
                                           unsigned short* __restrict__ hb,
                                           float* __restrict__ asb,
                                           float* __restrict__ adb,
                                           unsigned* __restrict__ gmax,
                                           float* __restrict__ wlds,
                                           float (*smax)[4], int N) {
    constexpr int HH = (H == 4) ? 4 : 1;
    int lane = threadIdx.x & 63;
    int lrow = lane & 15;
    int kg = lane >> 4;

    // load full B into registers: 32 frags = 128 VGPRs
    bf16x8 B[32];
#pragma unroll
    for (int ct = 0; ct < 8; ct++)
#pragma unroll
        for (int kk = 0; kk < 4; kk++)
            B[ct * 4 + kk] = *(const bf16x8*)(Wt + (size_t)(ct * 16 + lrow) * 128 + kk * 32 + kg * 8);

    int ntiles = (N + 15) >> 4;
    float wmax = -1e30f;

    // A prefetch for first tile
    bf16x8 A[4];
    {
        int tt = (wid < ntiles) ? wid : 0;
        int arow = min(tt * 16 + lrow, N - 1);
        const bf16x8* ap = (const bf16x8*)(xb + (size_t)arow * 128 + kg * 8);
        A[0] = ap[0]; A[1] = ap[4]; A[2] = ap[8]; A[3] = ap[12];
    }

    for (int t = wid; t < ntiles; t += nwaves) {
        // prefetch next tile's A
        bf16x8 An[4];
        {
            int tn = (t + nwaves < ntiles) ? t + nwaves : t;
            int arow = min(tn * 16 + lrow, N - 1);
            const bf16x8* ap = (const bf16x8*)(xb + (size_t)arow * 128 + kg * 8);
            An[0] = ap[0]; An[1] = ap[4]; An[2] = ap[8]; An[3] = ap[12];
        }
        f32x4 acc[8];
#pragma unroll
        for (int ct = 0; ct < 8; ct++) acc[ct] = (f32x4)0.f;
#pragma unroll
        for (int kk = 0; kk < 4; kk++)
#pragma unroll
            for (int ct = 0; ct < 8; ct++)
                acc[ct] = __builtin_amdgcn_mfma_f32_16x16x32_bf16(A[kk], B[ct * 4 + kk], acc[ct], 0, 0, 0);

        // stage fp32 acc to LDS: row = kg*4+reg, col = ct*16+lrow, stride 132 floats
#pragma unroll
        for (int ct = 0; ct < 8; ct++)
#pragma unroll
            for (int reg = 0; reg < 4; reg++)
                wlds[(kg * 4 + reg) * 132 + ct * 16 + lrow] = acc[ct][reg];

        // readback row-contiguous: lane = (row = lrow, seg = kg), 32 cols per lane
        const float* rp = wlds + lrow * 132 + kg * 32;
        const float* asp = a_s + kg * 32;
        const float* adp = a_d + kg * 32;
        float hv[32];
        float s = 0.f, d = 0.f;
#pragma unroll
        for (int q = 0; q < 8; q++) {
            float4 v = *(const float4*)(rp + q * 4);
            float4 av = *(const float4*)(asp + q * 4);
            float4 dv = *(const float4*)(adp + q * 4);
            hv[q * 4 + 0] = v.x; hv[q * 4 + 1] = v.y; hv[q * 4 + 2] = v.z; hv[q * 4 + 3] = v.w;
            s += v.x * av.x + v.y * av.y + v.z * av.z + v.w * av.w;
            d += v.x * dv.x + v.y * dv.y + v.z * dv.z + v.w * dv.w;
        }
        if (H == 1) {
            s += __shfl_xor(s, 16); s += __shfl_xor(s, 32);
            d += __shfl_xor(d, 16); d += __shfl_xor(d, 32);
        }
        int r = t * 16 + lrow;
        bool valid = r < N;
        if (valid) {
            if (H == 4) {
                asb[(size_t)r * 4 + kg] = s;
                adb[(size_t)r * 4 + kg] = d;
            } else if (kg == 0) {
                asb[r] = s;
                adb[r] = d;
            }
        }
        wmax = fmaxf(wmax, valid ? s : -1e30f);
        // pack bf16 + wide store (4 x dwordx4 per lane = lane's 32 cols)
        unsigned st[16];
#pragma unroll
        for (int q = 0; q < 16; q++)
            st[q] = (unsigned)f2bf(hv[2 * q]) | ((unsigned)f2bf(hv[2 * q + 1]) << 16);
        if (valid) {
            uint4* dst = (uint4*)(hb + (size_t)r * 128 + kg * 32);
            uint4 s0; s0.x = st[0];  s0.y = st[1];  s0.z = st[2];  s0.w = st[3];
            uint4 s1; s1.x = st[4];  s1.y = st[5];  s1.z = st[6];  s1.w = st[7];
            uint4 s2; s2.x = st[8];  s2.y = st[9];  s2.z = st[10]; s2.w = st[11];
            uint4 s3; s3.x = st[12]; s3.y = st[13]; s3.z = st[14]; s3.w = st[15];
            dst[0] = s0; dst[1] = s1; dst[2] = s2; dst[3] = s3;
        }
#pragma unroll
        for (int q = 0; q < 4; q++) A[q] = An[q];
    }

    // per-head global max: reduce lanes -> wave slot -> block -> atomic
    if (H == 4) {
        wmax = fmaxf(wmax, __shfl_xor(wmax, 1));
        wmax = fmaxf(wmax, __shfl_xor(wmax, 2));
        wmax = fmaxf(wmax, __shfl_xor(wmax, 4));
        wmax = fmaxf(wmax, __shfl_xor(wmax, 8));
        if (lrow == 0) smax[wave][kg] = wmax;      // lane's head = kg
    } else {
        wmax = fmaxf(wmax, __shfl_xor(wmax, 1));
        wmax = fmaxf(wmax, __shfl_xor(wmax, 2));
        wmax = fmaxf(wmax, __shfl_xor(wmax, 4));
        wmax = fmaxf(wmax, __shfl_xor(wmax, 8));
        wmax = fmaxf(wmax, __shfl_xor(wmax, 16));
        wmax = fmaxf(wmax, __shfl_xor(wmax, 32));
        if (lane == 0) smax[wave][0] = wmax;
    }
    __syncthreads();
    if (threadIdx.x < HH) {
        float m = fmaxf(fmaxf(smax[0][threadIdx.x], smax[1][threadIdx.x]),
                        fmaxf(smax[2][threadIdx.x], smax[3][threadIdx.x]));
        atomicMax(&gmax[threadIdx.x], fenc(m));
    }
    if (wid == 0 && threadIdx.x == 0) {
#pragma unroll
        for (int hd = 0; hd < HH; hd++) asb[(size_t)N * H + hd] = -1e30f;  // dummy -> p=0
    }
}

// ---- dispatches ----

__global__ __launch_bounds__(256, 2) void gemm1_scatter(const unsigned short* __restrict__ xb,
                                                        const unsigned short* __restrict__ Wt,
                                                        const float* __restrict__ a_s,
                                                        const float* __restrict__ a_d,
                                                        unsigned short* __restrict__ hb,
                                                        float* __restrict__ asb,
                                                        float* __restrict__ adb,
                                                        unsigned* __restrict__ gmax,
                                                        const int* __restrict__ ei, int E,
                                                        int* __restrict__ cursor,
                                                        unsigned short* __restrict__ srcs,
                                                        int N, int pn) {
    __shared__ float lds[4][16 * 132];
    __shared__ float smax[4][4];
    if ((int)blockIdx.x < GB) {
        int wave = threadIdx.x >> 6;
        gemm_body2<4>(blockIdx.x * 4 + wave, GB * 4, wave, xb, Wt, a_s, a_d,
                      hb, asb, adb, gmax, lds[wave], smax, N);
    } else {
        scatter_body(blockIdx.x - GB, threadIdx.x, ei, E, N, cursor, srcs, pn);
    }
}

__global__ __launch_bounds__(256, 2) void gemm2_pad(const unsigned short* __restrict__ xb,
                                                    const unsigned short* __restrict__ Wt,
                                                    const float* __restrict__ a_s,
                                                    const float* __restrict__ a_d,
                                                    unsigned short* __restrict__ hb,
                                                    float* __restrict__ asb,
                                                    float* __restrict__ adb,
                                                    unsigned* __restrict__ gmax,
                                                    int* __restrict__ cursor,
                                                    unsigned short* __restrict__ srcs, int N) {
    __shared__ float lds[4][16 * 132];
    __shared__ float smax[4][4];
    if ((int)blockIdx.x < GB) {
        int wave = threadIdx.x >> 6;
        gemm_body2<4>(blockIdx.x * 4 + wave, GB * 4, wave, xb, Wt, a_s, a_d,
                      hb, asb, adb, gmax, lds[wave], smax, N);
    } else {
        pad_body(blockIdx.x - GB, threadIdx.x, cursor, srcs, N);
    }
}

__global__ __launch_bounds__(256, 2) void gemm3_k(const unsigned short* __restrict__ xb,
                                                  const unsigned short* __restrict__ Wt,
                                                  const float* __restrict__ a_s,
                                                  const float* __restrict__ a_d,
                                                  unsigned short* __restrict__ hb,
                                                  float* __restrict__ asb,
                                                  float* __restrict__ adb,
                                                  unsigned* __restrict__ gmax, int N) {
    __shared__ float lds[4][16 * 132];
    __shared__ float smax[4][4];
    int wave = threadIdx.x >> 6;
    gemm_body2<1>(blockIdx.x * 4 + wave, GB * 4, wave, xb, Wt, a_s, a_d,
                  hb, asb, adb, gmax, lds[wave], smax, N);
}

// ---- aggregation: quarter-wave per dst, exp-dedup, 2-quad pipeline.
//      MASK=true: tail-quad masking from raw cursor (layer 1, pre-pad) ----

template <int H, bool RELU, bool OUTBF, bool MASK>
__global__ __launch_bounds__(256) void aggregate10(const unsigned short* __restrict__ hb,
                                                   const unsigned short* __restrict__ srcs,
                                                   const int* __restrict__ qn,
                                                   const float* __restrict__ asb,
                                                   const float* __restrict__ adb,
                                                   const unsigned* __restrict__ gmax,
                                                   const float* __restrict__ bias,
                                                   void* __restrict__ outv, int N) {
    int n = (blockIdx.x * 256 + threadIdx.x) >> 4;     // quarter-wave id = node
    if (n >= N) return;
    unsigned l = threadIdx.x & 15;
    unsigned ht = (H == 4) ? (l >> 2) : 0;
    int base = (threadIdx.x & 63) & ~15;               // quarter-wave base lane in wave
    float adn = adb[(unsigned)n * H + ht];
    float m = lrelu(fdec(gmax[ht]) + adn);
    const unsigned short* sp = srcs + ((size_t)n << 6);
    const uint4* hrow = (const uint4*)hb;              // 16 uint4 per 128-ch row
    int cv = qn[n];
    int nb, rem;
    if (MASK) {
        int dr = cv - (n << 6);
        dr = min(dr, 64);
        nb = (dr + 3) >> 2;
        rem = dr - ((nb - 1) << 2);                    // valid slots in final quad, 1..4
    } else {
        nb = cv;
        rem = 4;
    }
    float a0 = 0.f, a1 = 0.f, a2 = 0.f, a3 = 0.f;
    float a4 = 0.f, a5 = 0.f, a6 = 0.f, a7 = 0.f, den = 0.f;

    ushort4 sq = *(const ushort4*)sp;
    uint4 u0 = hrow[(unsigned)sq.x * 16u + l];
    uint4 u1 = hrow[(unsigned)sq.y * 16u + l];
    uint4 u2 = hrow[(unsigned)sq.z * 16u + l];
    uint4 u3 = hrow[(unsigned)sq.w * 16u + l];
    for (int j = 0; j < nb; j++) {
        int jn = (j + 1 < nb) ? j + 1 : j;
        ushort4 sn = *(const ushort4*)(sp + jn * 4);
        uint4 v0 = hrow[(unsigned)sn.x * 16u + l];     // next-quad rows in flight
        uint4 v1 = hrow[(unsigned)sn.y * 16u + l];
        uint4 v2 = hrow[(unsigned)sn.z * 16u + l];
        uint4 v3 = hrow[(unsigned)sn.w * 16u + l];
        unsigned sown = sp[j * 4 + (l & 3)];
        float e = asb[sown * H + ht];
        float pown = __expf(lrelu(e + adn) - m);
        float p0 = __shfl(pown, base + (int)ht * 4 + 0);
        float p1 = __shfl(pown, base + (int)ht * 4 + 1);
        float p2 = __shfl(pown, base + (int)ht * 4 + 2);
        float p3 = __shfl(pown, base + (int)ht * 4 + 3);
        if (MASK) {
            int limit = (j == nb - 1) ? rem : 4;
            p1 = (1 < limit) ? p1 : 0.f;
            p2 = (2 < limit) ? p2 : 0.f;
            p3 = (3 < limit) ? p3 : 0.f;
        }
        a0 += p0 * bflo(u0.x); a1 += p0 * bfhi(u0.x); a2 += p0 * bflo(u0.y); a3 += p0 * bfhi(u0.y);
        a4 += p0 * bflo(u0.z); a5 += p0 * bfhi(u0.z); a6 += p0 * bflo(u0.w); a7 += p0 * bfhi(u0.w);
        a0 += p1 * bflo(u1.x); a1 += p1 * bfhi(u1.x); a2 += p1 * bflo(u1.y); a3 += p1 * bfhi(u1.y);
        a4 += p1 * bflo(u1.z); a5 += p1 * bfhi(u1.z); a6 += p1 * bflo(u1.w); a7 += p1 * bfhi(u1.w);
        a0 += p2 * bflo(u2.x); a1 += p2 * bfhi(u2.x); a2 += p2 * bflo(u2.y); a3 += p2 * bfhi(u2.y);
        a4 += p2 * bflo(u2.z); a5 += p2 * bfhi(u2.z); a6 += p2 * bflo(u2.w); a7 += p2 * bfhi(u2.w);
        a0 += p3 * bflo(u3.x); a1 += p3 * bfhi(u3.x); a2 += p3 * bflo(u3.y); a3 += p3 * bfhi(u3.y);
        a4 += p3 * bflo(u3.z); a5 += p3 * bfhi(u3.z); a6 += p3 * bflo(u3.w); a7 += p3 * bfhi(u3.w);
        den += p0 + p1 + p2 + p3;
        sq = sn; u0 = v0; u1 = v1; u2 = v2; u3 = v3;
    }
    float inv = 1.f / (den + 1e-16f);
    unsigned c = l * 8;
    float4 bv0 = *(const float4*)&bias[c];
    float4 bv1 = *(const float4*)&bias[c + 4];
    float o0 = a0 * inv + bv0.x, o1 = a1 * inv + bv0.y;
    float o2 = a2 * inv + bv0.z, o3 = a3 * inv + bv0.w;
    float o4 = a4 * inv + bv1.x, o5 = a5 * inv + bv1.y;
    float o6 = a6 * inv + bv1.z, o7 = a7 * inv + bv1.w;
    if (RELU) {
        o0 = fmaxf(o0, 0.f); o1 = fmaxf(o1, 0.f); o2 = fmaxf(o2, 0.f); o3 = fmaxf(o3, 0.f);
        o4 = fmaxf(o4, 0.f); o5 = fmaxf(o5, 0.f); o6 = fmaxf(o6, 0.f); o7 = fmaxf(o7, 0.f);
    }
    if (OUTBF) {
        uint4 st;
        st.x = (unsigned)f2bf(o0) | ((unsigned)f2bf(o1) << 16);
        st.y = (unsigned)f2bf(o2) | ((unsigned)f2bf(o3) << 16);
        st.z = (unsigned)f2bf(o4) | ((unsigned)f2bf(o5) << 16);
        st.w = (unsigned)f2bf(o6) | ((unsigned)f2bf(o7) << 16);
        *(uint4*)&((unsigned short*)outv)[(size_t)n * 128 + c] = st;
    } else {
        float* op = (float*)outv + (size_t)n * 128 + c;
        float4 s0; s0.x = o0; s0.y = o1; s0.z = o2; s0.w = o3;
        float4 s1; s1.x = o4; s1.y = o5; s1.z = o6; s1.w = o7;
        *(float4*)op = s0;
        *(float4*)(op + 4) = s1;
    }
}

// ---------------- launch ----------------

extern "C" void kernel_launch(void* const* d_in, const int* in_sizes, int n_in,
                              void* d_out, int out_size, void* d_ws, size_t ws_size,
                              hipStream_t stream) {
    const float* x   = (const float*)d_in[0];
    const int*   ei  = (const int*)d_in[1];
    const float* W1  = (const float*)d_in[2];
    const float* as1 = (const float*)d_in[3];
    const float* ad1 = (const float*)d_in[4];
    const float* b1  = (const float*)d_in[5];
    const float* W2  = (const float*)d_in[6];
    const float* as2 = (const float*)d_in[7];
    const float* ad2 = (const float*)d_in[8];
    const float* b2  = (const float*)d_in[9];
    const float* W3  = (const float*)d_in[10];
    const float* as3 = (const float*)d_in[11];
    const float* ad3 = (const float*)d_in[12];
    const float* b3  = (const float*)d_in[13];

    const int N = in_sizes[0] / 128;
    const int E = in_sizes[1] / 2;
    const int PN = (N + 7) / 8;

    char* w = (char*)d_ws;
    size_t woff = 0;
    auto alloc = [&](size_t bytes) -> void* {
        void* p = w + woff;
        woff = (woff + bytes + 255) & ~(size_t)255;
        return p;
    };
    int*      cursor = (int*)alloc((size_t)(N + 1) * 4);
    unsigned short* srcs = (unsigned short*)alloc(((size_t)N * 64 + 64) * 2);
    float*    asb    = (float*)alloc((size_t)(N + 1) * 4 * 4);
    float*    adb    = (float*)alloc((size_t)(N + 1) * 4 * 4);
    unsigned* gmax   = (unsigned*)alloc(16 * 4);
    unsigned short* hb  = (unsigned short*)alloc((size_t)(N + 1) * 128 * 2);
    unsigned short* xb  = (unsigned short*)alloc((size_t)N * 128 * 2);
    unsigned short* Wt1 = (unsigned short*)alloc(128 * 128 * 2);
    unsigned short* Wt2 = (unsigned short*)alloc(128 * 128 * 2);
    unsigned short* Wt3 = (unsigned short*)alloc(128 * 128 * 2);
    float* outf = (float*)d_out;

    const int GX = (N * 32 + 255) / 256;
    const int ga = (N * 16 + 255) / 256;
    const int PB = (N + 255) / 256;

    // 1) setup: conversions + cursor/self-loop/gmax/dummy-row inits
    setup_all<<<GX + 192, 256, 0, stream>>>(x, W1, W2, W3, xb, Wt1, Wt2, Wt3,
                                            cursor, srcs, gmax, hb, N, GX);

    // 2) layer-1 GEMM (B-resident) || CSR scatter
    gemm1_scatter<<<GB + SB, 256, 0, stream>>>(xb, Wt1, as1, ad1, hb, asb, adb, gmax + 0,
                                               ei, E, cursor, srcs, N, PN);

    // 3) layer-1 aggregate with inline tail-masking (raw cursor)
    aggregate10<4, true, true, true><<<ga, 256, 0, stream>>>(hb, srcs, cursor, asb, adb,
                                                             gmax + 0, b1, xb, N);

    // 4) layer-2 GEMM || pad_fill (pads srcs, cursor -> quad count)
    gemm2_pad<<<GB + PB, 256, 0, stream>>>(xb, Wt2, as2, ad2, hb, asb, adb, gmax + 4,
                                           cursor, srcs, N);

    // 5) layer-2 aggregate (padded fast path)
    aggregate10<4, true, true, false><<<ga, 256, 0, stream>>>(hb, srcs, cursor, asb, adb,
                                                              gmax + 4, b2, xb, N);

    // 6) layer-3 GEMM (H=1)
    gemm3_k<<<GB, 256, 0, stream>>>(xb, Wt3, as3, ad3, hb, asb, adb, gmax + 8, N);

    // 7) layer-3 aggregate (fp32 out)
    aggregate10<1, false, false, false><<<ga, 256, 0, stream>>>(hb, srcs, cursor, asb, adb,
                                                                gmax + 8, b3, outf, N);
}

// Round 18
// 222.623 us; speedup vs baseline: 1.0840x; 1.0374x over previous
//
#include <hip/hip_runtime.h>
#include <hip/hip_bf16.h>
#include <math.h>

#define NPART 8
#define GB 512           // B-resident gemm blocks (4 waves each)

typedef __attribute__((ext_vector_type(8))) short bf16x8;
typedef __attribute__((ext_vector_type(4))) float f32x4;

__device__ __forceinline__ float lrelu(float v) { return fmaxf(v, 0.2f * v); }

__device__ __forceinline__ unsigned fenc(float f) {
    unsigned u = __float_as_uint(f);
    return (u & 0x80000000u) ? ~u : (u | 0x80000000u);
}
__device__ __forceinline__ float fdec(unsigned u) {
    return __uint_as_float((u & 0x80000000u) ? (u & 0x7FFFFFFFu) : ~u);
}
__device__ __forceinline__ unsigned short f2bf(float f) {
    union { __hip_bfloat16 b; unsigned short u; } cv;
    cv.b = __float2bfloat16(f);
    return cv.u;
}
__device__ __forceinline__ float bflo(unsigned u) { return __uint_as_float(u << 16); }
__device__ __forceinline__ float bfhi(unsigned u) { return __uint_as_float(u & 0xFFFF0000u); }

// ---- setup: x->xb bf16, W->Wt bf16, cursor/self-loop/gmax/dummy-row inits ----

__global__ void setup_all(const float* __restrict__ x,
                          const float* __restrict__ W1, const float* __restrict__ W2,
                          const float* __restrict__ W3,
                          unsigned short* __restrict__ xb,
                          unsigned short* __restrict__ Wt1, unsigned short* __restrict__ Wt2,
                          unsigned short* __restrict__ Wt3,
                          int* __restrict__ cursor, unsigned short* __restrict__ srcs,
                          unsigned* __restrict__ gmax, unsigned short* __restrict__ hb,
                          int N, int GX) {
    int b = blockIdx.x, t = threadIdx.x;
    if (b < GX) {                                   // role A: x conversion + inits
        int i = b * 256 + t;
        if (i < N * 32) {
            float4 v = ((const float4*)x)[i];
            ushort4 o;
            o.x = f2bf(v.x); o.y = f2bf(v.y); o.z = f2bf(v.z); o.w = f2bf(v.w);
            ((ushort4*)xb)[i] = o;
        }
        if (i < N) {
            cursor[i] = (i << 6) + 1;               // slot 0 = self-loop
            srcs[(size_t)i << 6] = (unsigned short)i;
        }
        if (i < 12) gmax[i] = fenc(-1e30f);
        if (i < 64) ((unsigned*)hb)[(size_t)N * 64 + i] = 0;   // dummy row N = 0
        return;
    }
    {                                               // role B: W transpose-convert
        int j = (b - GX) * 256 + t;
        if (j < 3 * 16384) {
            int mm = j >> 14, e = j & 16383;
            const float* W = (mm == 0) ? W1 : (mm == 1) ? W2 : W3;
            unsigned short* Wt = (mm == 0) ? Wt1 : (mm == 1) ? Wt2 : Wt3;
            int k = e >> 7, c = e & 127;
            Wt[c * 128 + k] = f2bf(W[e]);           // Wt[col][k]
        }
    }
}

// ---- scatter: standalone, XCD-partitioned, fixed-capacity CSR (64 slots/node) ----

__global__ void scatter_part(const int* __restrict__ ei, int E, int N,
                             int* cursor, unsigned short* __restrict__ srcs, int pn) {
    int part = blockIdx.x & (NPART - 1);
    int nb = gridDim.x >> 3;
    int chunk = blockIdx.x >> 3;
    int stride = nb * blockDim.x;
    int lo = part * pn, hi = min(lo + pn, N);
    for (int i = chunk * blockDim.x + threadIdx.x; i < E; i += stride) {
        int d = ei[E + i];
        if (d >= lo && d < hi) {
            int pos = atomicAdd(&cursor[d], 1);
            if (pos - (d << 6) < 64) srcs[pos] = (unsigned short)ei[i];
        }
    }
}

// ---- pad body (runs as tail of gemm2 dispatch) ----

__device__ __forceinline__ void pad_body(int pb, int t, int* __restrict__ cursor,
                                         unsigned short* __restrict__ srcs, int N) {
    int n = pb * 256 + t;
    if (n >= N) return;
    int dr = cursor[n] - (n << 6);
    if (dr > 64) dr = 64;
    int q = (dr + 3) >> 2;
    for (int k = dr; k < q * 4; k++) srcs[(n << 6) + k] = (unsigned short)N;
    cursor[n] = q;                                  // cursor -> quad count (layers 2,3)
}

// ---- B-resident MFMA GEMM body: wave holds full Wt in VGPRs, loops over 16-row tiles.
//      Epilogue: fp32 LDS transpose -> row-contiguous logits + wide bf16 stores. ----

template <int H>
__device__ __forceinline__ void gemm_body2(int wid, int nwaves, int wave,
                                           const unsigned short* __restrict__ xb,
                                           const unsigned short* __restrict__ Wt,
                                           const float* __restrict__ a_s,
                                           const float* __restrict__ a_d,
                                           unsigned short* __restrict__ hb,
                                           float* __restrict__ asb,
                                           float* __restrict__ adb,
                                           unsigned* __restrict__ gmax,
                                           float* __restrict__ wlds,
                                           float (*smax)[4], int N) {
    constexpr int HH = (H == 4) ? 4 : 1;
    int lane = threadIdx.x & 63;
    int lrow = lane & 15;
    int kg = lane >> 4;

    // load full B into registers: 32 frags = 128 VGPRs
    bf16x8 B[32];
#pragma unroll
    for (int ct = 0; ct < 8; ct++)
#pragma unroll
        for (int kk = 0; kk < 4; kk++)
            B[ct * 4 + kk] = *(const bf16x8*)(Wt + (size_t)(ct * 16 + lrow) * 128 + kk * 32 + kg * 8);

    int ntiles = (N + 15) >> 4;
    float wmax = -1e30f;

    // A prefetch for first tile
    bf16x8 A[4];
    {
        int tt = (wid < ntiles) ? wid : 0;
        int arow = min(tt * 16 + lrow, N - 1);
        const bf16x8* ap = (const bf16x8*)(xb + (size_t)arow * 128 + kg * 8);
        A[0] = ap[0]; A[1] = ap[4]; A[2] = ap[8]; A[3] = ap[12];
    }

    for (int t = wid; t < ntiles; t += nwaves) {
        // prefetch next tile's A
        bf16x8 An[4];
        {
            int tn = (t + nwaves < ntiles) ? t + nwaves : t;
            int arow = min(tn * 16 + lrow, N - 1);
            const bf16x8* ap = (const bf16x8*)(xb + (size_t)arow * 128 + kg * 8);
            An[0] = ap[0]; An[1] = ap[4]; An[2] = ap[8]; An[3] = ap[12];
        }
        f32x4 acc[8];
#pragma unroll
        for (int ct = 0; ct < 8; ct++) acc[ct] = (f32x4)0.f;
#pragma unroll
        for (int kk = 0; kk < 4; kk++)
#pragma unroll
            for (int ct = 0; ct < 8; ct++)
                acc[ct] = __builtin_amdgcn_mfma_f32_16x16x32_bf16(A[kk], B[ct * 4 + kk], acc[ct], 0, 0, 0);

        // stage fp32 acc to LDS: row = kg*4+reg, col = ct*16+lrow, stride 132 floats
#pragma unroll
        for (int ct = 0; ct < 8; ct++)
#pragma unroll
            for (int reg = 0; reg < 4; reg++)
                wlds[(kg * 4 + reg) * 132 + ct * 16 + lrow] = acc[ct][reg];

        // readback row-contiguous: lane = (row = lrow, seg = kg), 32 cols per lane
        const float* rp = wlds + lrow * 132 + kg * 32;
        const float* asp = a_s + kg * 32;
        const float* adp = a_d + kg * 32;
        float hv[32];
        float s = 0.f, d = 0.f;
#pragma unroll
        for (int q = 0; q < 8; q++) {
            float4 v = *(const float4*)(rp + q * 4);
            float4 av = *(const float4*)(asp + q * 4);
            float4 dv = *(const float4*)(adp + q * 4);
            hv[q * 4 + 0] = v.x; hv[q * 4 + 1] = v.y; hv[q * 4 + 2] = v.z; hv[q * 4 + 3] = v.w;
            s += v.x * av.x + v.y * av.y + v.z * av.z + v.w * av.w;
            d += v.x * dv.x + v.y * dv.y + v.z * dv.z + v.w * dv.w;
        }
        if (H == 1) {
            s += __shfl_xor(s, 16); s += __shfl_xor(s, 32);
            d += __shfl_xor(d, 16); d += __shfl_xor(d, 32);
        }
        int r = t * 16 + lrow;
        bool valid = r < N;
        if (valid) {
            if (H == 4) {
                asb[(size_t)r * 4 + kg] = s;
                adb[(size_t)r * 4 + kg] = d;
            } else if (kg == 0) {
                asb[r] = s;
                adb[r] = d;
            }
        }
        wmax = fmaxf(wmax, valid ? s : -1e30f);
        // pack bf16 + wide store (4 x dwordx4 per lane = lane's 32 cols)
        unsigned st[16];
#pragma unroll
        for (int q = 0; q < 16; q++)
            st[q] = (unsigned)f2bf(hv[2 * q]) | ((unsigned)f2bf(hv[2 * q + 1]) << 16);
        if (valid) {
            uint4* dst = (uint4*)(hb + (size_t)r * 128 + kg * 32);
            uint4 s0; s0.x = st[0];  s0.y = st[1];  s0.z = st[2];  s0.w = st[3];
            uint4 s1; s1.x = st[4];  s1.y = st[5];  s1.z = st[6];  s1.w = st[7];
            uint4 s2; s2.x = st[8];  s2.y = st[9];  s2.z = st[10]; s2.w = st[11];
            uint4 s3; s3.x = st[12]; s3.y = st[13]; s3.z = st[14]; s3.w = st[15];
            dst[0] = s0; dst[1] = s1; dst[2] = s2; dst[3] = s3;
        }
#pragma unroll
        for (int q = 0; q < 4; q++) A[q] = An[q];
    }

    // per-head global max: reduce lanes -> wave slot -> block -> atomic
    if (H == 4) {
        wmax = fmaxf(wmax, __shfl_xor(wmax, 1));
        wmax = fmaxf(wmax, __shfl_xor(wmax, 2));
        wmax = fmaxf(wmax, __shfl_xor(wmax, 4));
        wmax = fmaxf(wmax, __shfl_xor(wmax, 8));
        if (lrow == 0) smax[wave][kg] = wmax;      // lane's head = kg
    } else {
        wmax = fmaxf(wmax, __shfl_xor(wmax, 1));
        wmax = fmaxf(wmax, __shfl_xor(wmax, 2));
        wmax = fmaxf(wmax, __shfl_xor(wmax, 4));
        wmax = fmaxf(wmax, __shfl_xor(wmax, 8));
        wmax = fmaxf(wmax, __shfl_xor(wmax, 16));
        wmax = fmaxf(wmax, __shfl_xor(wmax, 32));
        if (lane == 0) smax[wave][0] = wmax;
    }
    __syncthreads();
    if (threadIdx.x < HH) {
        float m = fmaxf(fmaxf(smax[0][threadIdx.x], smax[1][threadIdx.x]),
                        fmaxf(smax[2][threadIdx.x], smax[3][threadIdx.x]));
        atomicMax(&gmax[threadIdx.x], fenc(m));
    }
    if (wid == 0 && threadIdx.x == 0) {
#pragma unroll
        for (int hd = 0; hd < HH; hd++) asb[(size_t)N * H + hd] = -1e30f;  // dummy -> p=0
    }
}

// ---- dispatches ----

__global__ __launch_bounds__(256, 2) void gemm1_k(const unsigned short* __restrict__ xb,
                                                  const unsigned short* __restrict__ Wt,
                                                  const float* __restrict__ a_s,
                                                  const float* __restrict__ a_d,
                                                  unsigned short* __restrict__ hb,
                                                  float* __restrict__ asb,
                                                  float* __restrict__ adb,
                                                  unsigned* __restrict__ gmax, int N) {
    __shared__ float lds[4][16 * 132];
    __shared__ float smax[4][4];
    int wave = threadIdx.x >> 6;
    gemm_body2<4>(blockIdx.x * 4 + wave, GB * 4, wave, xb, Wt, a_s, a_d,
                  hb, asb, adb, gmax, lds[wave], smax, N);
}

__global__ __launch_bounds__(256, 2) void gemm2_pad(const unsigned short* __restrict__ xb,
                                                    const unsigned short* __restrict__ Wt,
                                                    const float* __restrict__ a_s,
                                                    const float* __restrict__ a_d,
                                                    unsigned short* __restrict__ hb,
                                                    float* __restrict__ asb,
                                                    float* __restrict__ adb,
                                                    unsigned* __restrict__ gmax,
                                                    int* __restrict__ cursor,
                                                    unsigned short* __restrict__ srcs, int N) {
    __shared__ float lds[4][16 * 132];
    __shared__ float smax[4][4];
    if ((int)blockIdx.x < GB) {
        int wave = threadIdx.x >> 6;
        gemm_body2<4>(blockIdx.x * 4 + wave, GB * 4, wave, xb, Wt, a_s, a_d,
                      hb, asb, adb, gmax, lds[wave], smax, N);
    } else {
        pad_body(blockIdx.x - GB, threadIdx.x, cursor, srcs, N);
    }
}

__global__ __launch_bounds__(256, 2) void gemm3_k(const unsigned short* __restrict__ xb,
                                                  const unsigned short* __restrict__ Wt,
                                                  const float* __restrict__ a_s,
                                                  const float* __restrict__ a_d,
                                                  unsigned short* __restrict__ hb,
                                                  float* __restrict__ asb,
                                                  float* __restrict__ adb,
                                                  unsigned* __restrict__ gmax, int N) {
    __shared__ float lds[4][16 * 132];
    __shared__ float smax[4][4];
    int wave = threadIdx.x >> 6;
    gemm_body2<1>(blockIdx.x * 4 + wave, GB * 4, wave, xb, Wt, a_s, a_d,
                  hb, asb, adb, gmax, lds[wave], smax, N);
}

// ---- aggregation: quarter-wave per dst, exp-dedup, 2-quad pipeline.
//      MASK=true: tail-quad masking from raw cursor (layer 1, pre-pad) ----

template <int H, bool RELU, bool OUTBF, bool MASK>
__global__ __launch_bounds__(256) void aggregate10(const unsigned short* __restrict__ hb,
                                                   const unsigned short* __restrict__ srcs,
                                                   const int* __restrict__ qn,
                                                   const float* __restrict__ asb,
                                                   const float* __restrict__ adb,
                                                   const unsigned* __restrict__ gmax,
                                                   const float* __restrict__ bias,
                                                   void* __restrict__ outv, int N) {
    int n = (blockIdx.x * 256 + threadIdx.x) >> 4;     // quarter-wave id = node
    if (n >= N) return;
    unsigned l = threadIdx.x & 15;
    unsigned ht = (H == 4) ? (l >> 2) : 0;
    int base = (threadIdx.x & 63) & ~15;               // quarter-wave base lane in wave
    float adn = adb[(unsigned)n * H + ht];
    float m = lrelu(fdec(gmax[ht]) + adn);
    const unsigned short* sp = srcs + ((size_t)n << 6);
    const uint4* hrow = (const uint4*)hb;              // 16 uint4 per 128-ch row
    int cv = qn[n];
    int nb, rem;
    if (MASK) {
        int dr = cv - (n << 6);
        dr = min(dr, 64);
        nb = (dr + 3) >> 2;
        rem = dr - ((nb - 1) << 2);                    // valid slots in final quad, 1..4
    } else {
        nb = cv;
        rem = 4;
    }
    float a0 = 0.f, a1 = 0.f, a2 = 0.f, a3 = 0.f;
    float a4 = 0.f, a5 = 0.f, a6 = 0.f, a7 = 0.f, den = 0.f;

    ushort4 sq = *(const ushort4*)sp;
    uint4 u0 = hrow[(unsigned)sq.x * 16u + l];
    uint4 u1 = hrow[(unsigned)sq.y * 16u + l];
    uint4 u2 = hrow[(unsigned)sq.z * 16u + l];
    uint4 u3 = hrow[(unsigned)sq.w * 16u + l];
    for (int j = 0; j < nb; j++) {
        int jn = (j + 1 < nb) ? j + 1 : j;
        ushort4 sn = *(const ushort4*)(sp + jn * 4);
        uint4 v0 = hrow[(unsigned)sn.x * 16u + l];     // next-quad rows in flight
        uint4 v1 = hrow[(unsigned)sn.y * 16u + l];
        uint4 v2 = hrow[(unsigned)sn.z * 16u + l];
        uint4 v3 = hrow[(unsigned)sn.w * 16u + l];
        unsigned sown = sp[j * 4 + (l & 3)];
        float e = asb[sown * H + ht];
        float pown = __expf(lrelu(e + adn) - m);
        float p0 = __shfl(pown, base + (int)ht * 4 + 0);
        float p1 = __shfl(pown, base + (int)ht * 4 + 1);
        float p2 = __shfl(pown, base + (int)ht * 4 + 2);
        float p3 = __shfl(pown, base + (int)ht * 4 + 3);
        if (MASK) {
            int limit = (j == nb - 1) ? rem : 4;
            p1 = (1 < limit) ? p1 : 0.f;
            p2 = (2 < limit) ? p2 : 0.f;
            p3 = (3 < limit) ? p3 : 0.f;
        }
        a0 += p0 * bflo(u0.x); a1 += p0 * bfhi(u0.x); a2 += p0 * bflo(u0.y); a3 += p0 * bfhi(u0.y);
        a4 += p0 * bflo(u0.z); a5 += p0 * bfhi(u0.z); a6 += p0 * bflo(u0.w); a7 += p0 * bfhi(u0.w);
        a0 += p1 * bflo(u1.x); a1 += p1 * bfhi(u1.x); a2 += p1 * bflo(u1.y); a3 += p1 * bfhi(u1.y);
        a4 += p1 * bflo(u1.z); a5 += p1 * bfhi(u1.z); a6 += p1 * bflo(u1.w); a7 += p1 * bfhi(u1.w);
        a0 += p2 * bflo(u2.x); a1 += p2 * bfhi(u2.x); a2 += p2 * bflo(u2.y); a3 += p2 * bfhi(u2.y);
        a4 += p2 * bflo(u2.z); a5 += p2 * bfhi(u2.z); a6 += p2 * bflo(u2.w); a7 += p2 * bfhi(u2.w);
        a0 += p3 * bflo(u3.x); a1 += p3 * bfhi(u3.x); a2 += p3 * bflo(u3.y); a3 += p3 * bfhi(u3.y);
        a4 += p3 * bflo(u3.z); a5 += p3 * bfhi(u3.z); a6 += p3 * bflo(u3.w); a7 += p3 * bfhi(u3.w);
        den += p0 + p1 + p2 + p3;
        sq = sn; u0 = v0; u1 = v1; u2 = v2; u3 = v3;
    }
    float inv = 1.f / (den + 1e-16f);
    unsigned c = l * 8;
    float4 bv0 = *(const float4*)&bias[c];
    float4 bv1 = *(const float4*)&bias[c + 4];
    float o0 = a0 * inv + bv0.x, o1 = a1 * inv + bv0.y;
    float o2 = a2 * inv + bv0.z, o3 = a3 * inv + bv0.w;
    float o4 = a4 * inv + bv1.x, o5 = a5 * inv + bv1.y;
    float o6 = a6 * inv + bv1.z, o7 = a7 * inv + bv1.w;
    if (RELU) {
        o0 = fmaxf(o0, 0.f); o1 = fmaxf(o1, 0.f); o2 = fmaxf(o2, 0.f); o3 = fmaxf(o3, 0.f);
        o4 = fmaxf(o4, 0.f); o5 = fmaxf(o5, 0.f); o6 = fmaxf(o6, 0.f); o7 = fmaxf(o7, 0.f);
    }
    if (OUTBF) {
        uint4 st;
        st.x = (unsigned)f2bf(o0) | ((unsigned)f2bf(o1) << 16);
        st.y = (unsigned)f2bf(o2) | ((unsigned)f2bf(o3) << 16);
        st.z = (unsigned)f2bf(o4) | ((unsigned)f2bf(o5) << 16);
        st.w = (unsigned)f2bf(o6) | ((unsigned)f2bf(o7) << 16);
        *(uint4*)&((unsigned short*)outv)[(size_t)n * 128 + c] = st;
    } else {
        float* op = (float*)outv + (size_t)n * 128 + c;
        float4 s0; s0.x = o0; s0.y = o1; s0.z = o2; s0.w = o3;
        float4 s1; s1.x = o4; s1.y = o5; s1.z = o6; s1.w = o7;
        *(float4*)op = s0;
        *(float4*)(op + 4) = s1;
    }
}

// ---------------- launch ----------------

extern "C" void kernel_launch(void* const* d_in, const int* in_sizes, int n_in,
                              void* d_out, int out_size, void* d_ws, size_t ws_size,
                              hipStream_t stream) {
    const float* x   = (const float*)d_in[0];
    const int*   ei  = (const int*)d_in[1];
    const float* W1  = (const float*)d_in[2];
    const float* as1 = (const float*)d_in[3];
    const float* ad1 = (const float*)d_in[4];
    const float* b1  = (const float*)d_in[5];
    const float* W2  = (const float*)d_in[6];
    const float* as2 = (const float*)d_in[7];
    const float* ad2 = (const float*)d_in[8];
    const float* b2  = (const float*)d_in[9];
    const float* W3  = (const float*)d_in[10];
    const float* as3 = (const float*)d_in[11];
    const float* ad3 = (const float*)d_in[12];
    const float* b3  = (const float*)d_in[13];

    const int N = in_sizes[0] / 128;
    const int E = in_sizes[1] / 2;
    const int PN = (N + NPART - 1) / NPART;

    char* w = (char*)d_ws;
    size_t woff = 0;
    auto alloc = [&](size_t bytes) -> void* {
        void* p = w + woff;
        woff = (woff + bytes + 255) & ~(size_t)255;
        return p;
    };
    int*      cursor = (int*)alloc((size_t)(N + 1) * 4);
    unsigned short* srcs = (unsigned short*)alloc(((size_t)N * 64 + 64) * 2);
    float*    asb    = (float*)alloc((size_t)(N + 1) * 4 * 4);
    float*    adb    = (float*)alloc((size_t)(N + 1) * 4 * 4);
    unsigned* gmax   = (unsigned*)alloc(16 * 4);
    unsigned short* hb  = (unsigned short*)alloc((size_t)(N + 1) * 128 * 2);
    unsigned short* xb  = (unsigned short*)alloc((size_t)N * 128 * 2);
    unsigned short* Wt1 = (unsigned short*)alloc(128 * 128 * 2);
    unsigned short* Wt2 = (unsigned short*)alloc(128 * 128 * 2);
    unsigned short* Wt3 = (unsigned short*)alloc(128 * 128 * 2);
    float* outf = (float*)d_out;

    const int GX = (N * 32 + 255) / 256;
    const int ga = (N * 16 + 255) / 256;
    const int PB = (N + 255) / 256;

    // 1) setup: conversions + cursor/self-loop/gmax/dummy-row inits
    setup_all<<<GX + 192, 256, 0, stream>>>(x, W1, W2, W3, xb, Wt1, Wt2, Wt3,
                                            cursor, srcs, gmax, hb, N, GX);

    // 2) CSR scatter (standalone, full parallelism, zero LDS)
    scatter_part<<<2048, 256, 0, stream>>>(ei, E, N, cursor, srcs, PN);

    // 3) layer-1 GEMM (B-resident, standalone)
    gemm1_k<<<GB, 256, 0, stream>>>(xb, Wt1, as1, ad1, hb, asb, adb, gmax + 0, N);

    // 4) layer-1 aggregate with inline tail-masking (raw cursor)
    aggregate10<4, true, true, true><<<ga, 256, 0, stream>>>(hb, srcs, cursor, asb, adb,
                                                             gmax + 0, b1, xb, N);

    // 5) layer-2 GEMM || pad_fill (pads srcs, cursor -> quad count)
    gemm2_pad<<<GB + PB, 256, 0, stream>>>(xb, Wt2, as2, ad2, hb, asb, adb, gmax + 4,
                                           cursor, srcs, N);

    // 6) layer-2 aggregate (padded fast path)
    aggregate10<4, true, true, false><<<ga, 256, 0, stream>>>(hb, srcs, cursor, asb, adb,
                                                              gmax + 4, b2, xb, N);

    // 7) layer-3 GEMM (H=1)
    gemm3_k<<<GB, 256, 0, stream>>>(xb, Wt3, as3, ad3, hb, asb, adb, gmax + 8, N);

    // 8) layer-3 aggregate (fp32 out)
    aggregate10<1, false, false, false><<<ga, 256, 0, stream>>>(hb, srcs, cursor, asb, adb,
                                                                gmax + 8, b3, outf, N);
}